// Round 11
// baseline (42.144 us; speedup 1.0000x reference)
//
#include <hip/hip_runtime.h>

// GaitPINN: encoder MLP -> 2-D neural ODE (tanh MLP vector field) -> decoder.
// R11: two-kernel split (R10) + LDS-staged dense stores in the emit kernel.
// Kernel A (gait_integrate): encoder + RK4 (NSEG=12, 16 lanes/sample,
//   full-DPP allred16); stores 13 boundary (z,f) float4s to d_ws.
// Kernel B (gait_emit): block = (time m, 256-sample tile). Each thread
//   computes one sample's power-basis cubic Hermite + decoder into LDS laid
//   out exactly as the output; block then streams ztl/xhl as contiguous
//   float4 stores (1024B per wave-instruction). Fixes R10-B's xh scatter
//   (3 scalar stores @ 12B lane stride = 3x L2 write transactions on 48MB).
// Fallback: R9 fused kernel if ws_size is too small.
// Pinned-codegen lessons kept: #pragma unroll 1 serial loops (R3: compiler
// unroll blew VGPR 52->156), interchanged encoder, bo2 folded into lane 0.

constexpr int   BATCH = 16384;
constexpr int   NSEG  = 12;
constexpr float DT    = 1.0f / (float)NSEG;
constexpr float DT2   = DT * 0.5f;
constexpr float DT6   = DT / 6.0f;
constexpr float SCALE = 2.8853900817779268f; // 2*log2(e): tanh(s)=1-2/(1+exp2(SCALE*s))
constexpr float K255  = (float)NSEG / 255.0f; // theta = m*K255 - k

__device__ __forceinline__ float fast_exp2(float x) {
#if __has_builtin(__builtin_amdgcn_exp2f)
  return __builtin_amdgcn_exp2f(x);
#else
  return exp2f(x);
#endif
}

__device__ __forceinline__ float fast_rcp(float x) {
#if __has_builtin(__builtin_amdgcn_rcpf)
  return __builtin_amdgcn_rcpf(x);
#else
  return 1.0f / x;
#endif
}

// v += lane-permuted v, permutation given by DPP ctrl. Full-rate VALU.
template<int CTRL>
__device__ __forceinline__ float dpp_add(float v) {
  int sw = __builtin_amdgcn_update_dpp(0, __float_as_int(v), CTRL, 0xF, 0xF, true);
  return v + __int_as_float(sw);
}

// Butterfly allreduce over each aligned 16-lane group, all full-rate DPP:
// xor1 (quad_perm 0xB1), xor2 (quad_perm 0x4E), row_half_mirror (0x141),
// row_mirror (0x140). All 16 lanes end bitwise identical (verified R2-R10).
__device__ __forceinline__ float allred16(float v) {
  v = dpp_add<0xB1>(v);
  v = dpp_add<0x4E>(v);
  v = dpp_add<0x141>(v);
  v = dpp_add<0x140>(v);
  return v;
}

// ---------------------------------------------------------------------------
// Kernel A: encoder + RK4 integration; stores boundary (z, f) float4s.
// ---------------------------------------------------------------------------
__global__ __launch_bounds__(256) void gait_integrate(
    const float* __restrict__ x,
    const float* __restrict__ We1, const float* __restrict__ be1,
    const float* __restrict__ We2, const float* __restrict__ be2,
    const float* __restrict__ We3, const float* __restrict__ be3,
    const float* __restrict__ Wo1, const float* __restrict__ bo1,
    const float* __restrict__ Wo2, const float* __restrict__ bo2,
    float* __restrict__ out, float4* __restrict__ bnd)
{
  const int t   = blockIdx.x * 256 + threadIdx.x;
  const int b   = t >> 4;   // sample id
  const int sub = t & 15;   // lane within the sample's 16-lane group

  // ---------------- encoder, loop-interchanged (R4) ----------------
  const float* xb = x + (size_t)b * 2304;  // x[b, 0, :], row stride 256*9
  float xv[9];
#pragma unroll
  for (int i = 0; i < 9; ++i) xv[i] = xb[i];

  const int c0 = sub * 4;
  float s0 = be2[c0+0], s1 = be2[c0+1], s2 = be2[c0+2], s3 = be2[c0+3];
#pragma unroll 4
  for (int i = 0; i < 64; ++i) {
    float h = be1[i];
#pragma unroll
    for (int j = 0; j < 9; ++j) h = fmaf(xv[j], We1[j*64 + i], h);
    h = fmaxf(h, 0.0f);
    const float* w2r = We2 + i*64 + c0;
    s0 = fmaf(h, w2r[0], s0);
    s1 = fmaf(h, w2r[1], s1);
    s2 = fmaf(h, w2r[2], s2);
    s3 = fmaf(h, w2r[3], s3);
  }
  s0 = fmaxf(s0, 0.0f); s1 = fmaxf(s1, 0.0f);
  s2 = fmaxf(s2, 0.0f); s3 = fmaxf(s3, 0.0f);
  float z0a = fmaf(s0, We3[(c0+0)*2+0], fmaf(s1, We3[(c0+1)*2+0],
              fmaf(s2, We3[(c0+2)*2+0],      s3 * We3[(c0+3)*2+0])));
  float z0b = fmaf(s0, We3[(c0+0)*2+1], fmaf(s1, We3[(c0+1)*2+1],
              fmaf(s2, We3[(c0+2)*2+1],      s3 * We3[(c0+3)*2+1])));
  z0a = allred16(z0a) + be3[0];
  z0b = allred16(z0b) + be3[1];

  // write z0 (out[0 .. 32767])
  if (sub == 5) {
    float2 v; v.x = z0a; v.y = z0b;
    *reinterpret_cast<float2*>(out + (size_t)b * 2) = v;
  }

  // this lane's 2-wide slice of the 32 hidden units of the vector field
  float w1a[2], w1b[2], b1s[2], w2a[2], w2b[2];
  const int u0 = sub * 2;
#pragma unroll
  for (int q = 0; q < 2; ++q) {
    w1a[q] = Wo1[      u0 + q] * SCALE;   // Wo1[0][u]
    w1b[q] = Wo1[32 +  u0 + q] * SCALE;   // Wo1[1][u]
    b1s[q] = bo1[      u0 + q] * SCALE;
    w2a[q] = Wo2[(u0 + q)*2 + 0];
    w2b[q] = Wo2[(u0 + q)*2 + 1];
  }
  // bo2 folded into lane 0's accumulator init (xor-butterfly keeps all lanes
  // bitwise identical regardless of which lane carries the bias).
  const float a0i = (sub == 0) ? bo2[0] : 0.0f;
  const float a1i = (sub == 0) ? bo2[1] : 0.0f;

  auto vf = [&](float za, float zb, float& o0, float& o1) {
    float a0 = a0i, a1 = a1i;
#pragma unroll
    for (int q = 0; q < 2; ++q) {
      float u  = fmaf(za, w1a[q], fmaf(zb, w1b[q], b1s[q]));
      float e  = fast_exp2(u);
      float rr = fast_rcp(e + 1.0f);
      float th = fmaf(-2.0f, rr, 1.0f);     // tanh
      a0 = fmaf(th, w2a[q], a0);
      a1 = fmaf(th, w2b[q], a1);
    }
    o0 = allred16(a0);
    o1 = allred16(a1);
  };

  float za = z0a, zb = z0b;
  float fa, fb;
  vf(za, zb, fa, fb);        // k1 of first segment (carried across segments)

  // Boundary store: lane 0 of each group; lanes 0,16,32,48 of a wave write
  // 4 consecutive float4s -> one contiguous 64B line per wave per boundary.
  const bool storer = (sub == 0);
  float4* wrow = bnd + b;

  // #pragma unroll 1: R3 lesson — compiler unroll exploded VGPRs (52->156).
#pragma unroll 1
  for (int k = 0; k < NSEG; ++k) {
    if (storer) { float4 v; v.x = za; v.y = zb; v.z = fa; v.w = fb;
                  wrow[k * BATCH] = v; }
    float k2a, k2b, k3a, k3b, k4a, k4b, fna, fnb;
    vf(fmaf(DT2, fa,  za), fmaf(DT2, fb,  zb), k2a, k2b);
    vf(fmaf(DT2, k2a, za), fmaf(DT2, k2b, zb), k3a, k3b);
    vf(fmaf(DT,  k3a, za), fmaf(DT,  k3b, zb), k4a, k4b);
    float zna = fmaf(DT6, fa + k4a + 2.0f*(k2a + k3a), za);
    float znb = fmaf(DT6, fb + k4b + 2.0f*(k2b + k3b), zb);
    vf(zna, znb, fna, fnb);  // next segment's k1 + Hermite end-tangent
    za = zna; zb = znb; fa = fna; fb = fnb;
  }
  if (storer) { float4 v; v.x = za; v.y = zb; v.z = fa; v.w = fb;
                wrow[NSEG * BATCH] = v; }
}

// ---------------------------------------------------------------------------
// Kernel B: dense output. Block = (time m, 256-sample tile); LDS-staged
// output layout, streamed out as contiguous float4 stores.
// ---------------------------------------------------------------------------
__global__ __launch_bounds__(256) void gait_emit(
    const float4* __restrict__ bnd,
    const float* __restrict__ Wd, const float* __restrict__ bd,
    float* __restrict__ out)
{
  const int tid  = threadIdx.x;
  const int m    = blockIdx.x >> 6;          // 0..255 (uniform per block)
  const int tile = blockIdx.x & 63;          // 64 tiles of 256 samples
  const int b    = tile * 256 + tid;

  int k = (m * NSEG) / 255;                  // segment; exact integer math
  if (k > NSEG - 1) k = NSEG - 1;            // m=255 -> k=11, th=1
  const float th = fmaf((float)m, K255, -(float)k);

  const float4 p0 = bnd[k * BATCH + b];      // (z_k, f_k)   coalesced
  const float4 p1 = bnd[(k + 1) * BATCH + b];

  const float fadt  = DT * p0.z, fbdt  = DT * p0.w;
  const float fnadt = DT * p1.z, fnbdt = DT * p1.w;
  const float da = p1.x - p0.x, db = p1.y - p0.y;
  const float c2a = fmaf(3.f, da, -fmaf(2.f, fadt, fnadt));
  const float c3a = fmaf(-2.f, da, fadt + fnadt);
  const float c2b = fmaf(3.f, db, -fmaf(2.f, fbdt, fnbdt));
  const float c3b = fmaf(-2.f, db, fbdt + fnbdt);

  const float va = fmaf(fmaf(fmaf(c3a, th, c2a), th, fadt), th, p0.x);
  const float vb = fmaf(fmaf(fmaf(c3b, th, c2b), th, fbdt), th, p0.y);

  // Stage into LDS with EXACTLY the output layout, then stream out dense.
  __shared__ float ztl[512];   // (256 samples) x (2)  -> zt row chunk
  __shared__ float xhl[768];   // (256 samples) x (3)  -> xh row chunk
  ztl[2*tid + 0] = va;                                   // 2-way bank: free
  ztl[2*tid + 1] = vb;
  xhl[3*tid + 0] = fmaf(va, Wd[0], fmaf(vb, Wd[3], bd[0])); // stride-3: <=2-way
  xhl[3*tid + 1] = fmaf(va, Wd[1], fmaf(vb, Wd[4], bd[1]));
  xhl[3*tid + 2] = fmaf(va, Wd[2], fmaf(vb, Wd[5], bd[2]));
  __syncthreads();

  float* __restrict__ zt = out + 32768;
  float* __restrict__ xh = out + 32768 + 8388608;
  float4* ztg = reinterpret_cast<float4*>(zt + ((size_t)m << 15) + tile * 512);
  float4* xhg = reinterpret_cast<float4*>(xh + (size_t)m * 49152 + tile * 768);
  const float4* zts = reinterpret_cast<const float4*>(ztl);
  const float4* xhs = reinterpret_cast<const float4*>(xhl);
  if (tid < 128) ztg[tid] = zts[tid];        // 512 floats, contiguous
  if (tid < 192) xhg[tid] = xhs[tid];        // 768 floats, contiguous
}

// ---------------------------------------------------------------------------
// Fallback fused kernel (R9) — used only if ws_size is too small.
// ---------------------------------------------------------------------------
__global__ __launch_bounds__(256) void gait_fused(
    const float* __restrict__ x,
    const float* __restrict__ We1, const float* __restrict__ be1,
    const float* __restrict__ We2, const float* __restrict__ be2,
    const float* __restrict__ We3, const float* __restrict__ be3,
    const float* __restrict__ Wo1, const float* __restrict__ bo1,
    const float* __restrict__ Wo2, const float* __restrict__ bo2,
    const float* __restrict__ Wd,  const float* __restrict__ bd,
    float* __restrict__ out)
{
  const int t   = blockIdx.x * 256 + threadIdx.x;
  const int b   = t >> 4;
  const int sub = t & 15;

  const float* xb = x + (size_t)b * 2304;
  float xv[9];
#pragma unroll
  for (int i = 0; i < 9; ++i) xv[i] = xb[i];

  const int c0 = sub * 4;
  float s0 = be2[c0+0], s1 = be2[c0+1], s2 = be2[c0+2], s3 = be2[c0+3];
#pragma unroll 4
  for (int i = 0; i < 64; ++i) {
    float h = be1[i];
#pragma unroll
    for (int j = 0; j < 9; ++j) h = fmaf(xv[j], We1[j*64 + i], h);
    h = fmaxf(h, 0.0f);
    const float* w2r = We2 + i*64 + c0;
    s0 = fmaf(h, w2r[0], s0);
    s1 = fmaf(h, w2r[1], s1);
    s2 = fmaf(h, w2r[2], s2);
    s3 = fmaf(h, w2r[3], s3);
  }
  s0 = fmaxf(s0, 0.0f); s1 = fmaxf(s1, 0.0f);
  s2 = fmaxf(s2, 0.0f); s3 = fmaxf(s3, 0.0f);
  float z0a = fmaf(s0, We3[(c0+0)*2+0], fmaf(s1, We3[(c0+1)*2+0],
              fmaf(s2, We3[(c0+2)*2+0],      s3 * We3[(c0+3)*2+0])));
  float z0b = fmaf(s0, We3[(c0+0)*2+1], fmaf(s1, We3[(c0+1)*2+1],
              fmaf(s2, We3[(c0+2)*2+1],      s3 * We3[(c0+3)*2+1])));
  z0a = allred16(z0a) + be3[0];
  z0b = allred16(z0b) + be3[1];

  if (sub == 5) {
    float2 v; v.x = z0a; v.y = z0b;
    *reinterpret_cast<float2*>(out + (size_t)b * 2) = v;
  }

  float* __restrict__ zt = out + 32768;
  float* __restrict__ xh = out + 32768 + 8388608;

  const int r     = sub % 5;
  const int slot0 = (sub < 15) ? (sub / 5) : (1 << 20);
  float ca = 0.f, cb = 0.f, cc = 0.f;
  if      (r == 0) { ca = 1.f; }
  else if (r == 1) { cb = 1.f; }
  else if (r == 2) { ca = Wd[0]; cb = Wd[3]; cc = bd[0]; }
  else if (r == 3) { ca = Wd[1]; cb = Wd[4]; cc = bd[1]; }
  else             { ca = Wd[2]; cb = Wd[5]; cc = bd[2]; }
  float* pbase = (r < 2) ? (zt + (size_t)b * 2 + r)
                         : (xh + (size_t)b * 3 + (r - 2));
  const uint32_t pstride  = (r < 2) ? 32768u : 49152u;
  const uint32_t pstride3 = 3u * pstride;

  if (sub < 5) pbase[0] = fmaf(z0a, ca, fmaf(z0b, cb, cc));

  float w1a[2], w1b[2], b1s[2], w2a[2], w2b[2];
  const int u0 = sub * 2;
#pragma unroll
  for (int q = 0; q < 2; ++q) {
    w1a[q] = Wo1[      u0 + q] * SCALE;
    w1b[q] = Wo1[32 +  u0 + q] * SCALE;
    b1s[q] = bo1[      u0 + q] * SCALE;
    w2a[q] = Wo2[(u0 + q)*2 + 0];
    w2b[q] = Wo2[(u0 + q)*2 + 1];
  }
  const float a0i = (sub == 0) ? bo2[0] : 0.0f;
  const float a1i = (sub == 0) ? bo2[1] : 0.0f;

  auto vf = [&](float za, float zb, float& o0, float& o1) {
    float a0 = a0i, a1 = a1i;
#pragma unroll
    for (int q = 0; q < 2; ++q) {
      float u  = fmaf(za, w1a[q], fmaf(zb, w1b[q], b1s[q]));
      float e  = fast_exp2(u);
      float rr = fast_rcp(e + 1.0f);
      float th = fmaf(-2.0f, rr, 1.0f);
      a0 = fmaf(th, w2a[q], a0);
      a1 = fmaf(th, w2b[q], a1);
    }
    o0 = allred16(a0);
    o1 = allred16(a1);
  };

  float pC0 = 0.f, pC1 = 0.f, pC2 = 0.f, pC3 = 0.f, pkneg = 0.f;
  int   pim0 = 0, pml = -1;
  uint32_t poff = 0;

  auto emit4 = [&](int jb) {
#pragma unroll
    for (int j = 0; j < 4; ++j) {
      const int im = pim0 + 3 * (jb + j);
      if (im <= pml) {
        const float th = fmaf((float)im, K255, pkneg);
        pbase[poff + (uint32_t)(jb + j) * pstride3] =
            fmaf(fmaf(fmaf(pC3, th, pC2), th, pC1), th, pC0);
      }
    }
  };

  float za = z0a, zb = z0b;
  float fa, fb;
  vf(za, zb, fa, fb);

#pragma unroll 1
  for (int k = 0; k < NSEG; ++k) {
    float k2a, k2b, k3a, k3b, k4a, k4b, fna, fnb;
    vf(fmaf(DT2, fa,  za), fmaf(DT2, fb,  zb), k2a, k2b);
    emit4(0);
    vf(fmaf(DT2, k2a, za), fmaf(DT2, k2b, zb), k3a, k3b);
    emit4(4);
    vf(fmaf(DT,  k3a, za), fmaf(DT,  k3b, zb), k4a, k4b);
    float zna = fmaf(DT6, fa + k4a + 2.0f*(k2a + k3a), za);
    float znb = fmaf(DT6, fb + k4b + 2.0f*(k2b + k3b), zb);
    vf(zna, znb, fna, fnb);

    const float da_ = zna - za, db_ = znb - zb;
    const float D  = fmaf(ca, da_, cb * db_);
    pC1 = DT * fmaf(ca, fa,  cb * fb);
    const float Fn = DT * fmaf(ca, fna, cb * fnb);
    pC2 = fmaf(3.f, D, -fmaf(2.f, pC1, Fn));
    pC3 = fmaf(-2.f, D, pC1 + Fn);
    pC0 = fmaf(ca, za, fmaf(cb, zb, cc));
    const int m0 = (255 * k) / NSEG + 1;
    pml  = (255 * (k + 1)) / NSEG;
    pim0 = m0 + slot0;
    pkneg = -(float)k;
    poff  = (uint32_t)pim0 * pstride;

    za = zna; zb = znb; fa = fna; fb = fnb;
  }
  emit4(0);
  emit4(4);
}

extern "C" void kernel_launch(void* const* d_in, const int* in_sizes, int n_in,
                              void* d_out, int out_size, void* d_ws, size_t ws_size,
                              hipStream_t stream)
{
  const float* x   = (const float*)d_in[0];
  const float* We1 = (const float*)d_in[1];
  const float* be1 = (const float*)d_in[2];
  const float* We2 = (const float*)d_in[3];
  const float* be2 = (const float*)d_in[4];
  const float* We3 = (const float*)d_in[5];
  const float* be3 = (const float*)d_in[6];
  const float* Wo1 = (const float*)d_in[7];
  const float* bo1 = (const float*)d_in[8];
  const float* Wo2 = (const float*)d_in[9];
  const float* bo2 = (const float*)d_in[10];
  const float* Wd  = (const float*)d_in[11];
  const float* bd  = (const float*)d_in[12];

  const size_t need = (size_t)(NSEG + 1) * BATCH * sizeof(float4);
  if (ws_size >= need) {
    float4* bnd = (float4*)d_ws;
    dim3 blk(256);
    dim3 gA(BATCH * 16 / 256);
    gait_integrate<<<gA, blk, 0, stream>>>(x, We1, be1, We2, be2, We3, be3,
                                           Wo1, bo1, Wo2, bo2,
                                           (float*)d_out, bnd);
    dim3 gB(256 * 64);   // 256 time rows x 64 sample tiles
    gait_emit<<<gB, blk, 0, stream>>>(bnd, Wd, bd, (float*)d_out);
  } else {
    dim3 gA(BATCH * 16 / 256), blk(256);
    gait_fused<<<gA, blk, 0, stream>>>(x, We1, be1, We2, be2, We3, be3,
                                       Wo1, bo1, Wo2, bo2, Wd, bd,
                                       (float*)d_out);
  }
}

// Round 12
// 32.844 us; speedup vs baseline: 1.2832x; 1.2832x over previous
//
#include <hip/hip_runtime.h>

// GaitPINN: encoder MLP -> 2-D neural ODE (tanh MLP vector field) -> decoder.
// R12: single fused kernel. The R10/R11 two-kernel split imposed a grid-wide
// A->B drain (all integration before any emit) + 2nd launch + bnd HBM
// round-trip; but the dependency is per-sample only. Fuse: block = 16 samples
// x 16 lanes integrates (NSEG=12 RK4, full-DPP allred16, proven R4-R11),
// boundary (z,f) float4s -> LDS (13x16 = 3.3KB); one __syncthreads; same
// block emits all 256 time rows for its 16 samples (per-component power-basis
// cubic, arithmetic identical to R10/R11-B -> bit-identical output).
// Emit mapping: thread (s=tid&15, mpart=tid>>4), m = mpart+16*it: 16 lanes
// share one m -> zt float2 stores 128B-contiguous; xh scalar stores (R11
// proved the 12B-stride scatter costs nothing). Blocks in later waves
// integrate while earlier blocks emit -> phase overlap the split forbade.
// Pinned-codegen lessons kept: #pragma unroll 1 serial loops (R3: compiler
// unroll blew VGPR 52->156), interchanged encoder, bo2 folded into lane 0.

constexpr int   BATCH = 16384;
constexpr int   NSEG  = 12;
constexpr float DT    = 1.0f / (float)NSEG;
constexpr float DT2   = DT * 0.5f;
constexpr float DT6   = DT / 6.0f;
constexpr float SCALE = 2.8853900817779268f; // 2*log2(e): tanh(s)=1-2/(1+exp2(SCALE*s))
constexpr float K255  = (float)NSEG / 255.0f; // theta = m*K255 - k

__device__ __forceinline__ float fast_exp2(float x) {
#if __has_builtin(__builtin_amdgcn_exp2f)
  return __builtin_amdgcn_exp2f(x);
#else
  return exp2f(x);
#endif
}

__device__ __forceinline__ float fast_rcp(float x) {
#if __has_builtin(__builtin_amdgcn_rcpf)
  return __builtin_amdgcn_rcpf(x);
#else
  return 1.0f / x;
#endif
}

// v += lane-permuted v, permutation given by DPP ctrl. Full-rate VALU.
template<int CTRL>
__device__ __forceinline__ float dpp_add(float v) {
  int sw = __builtin_amdgcn_update_dpp(0, __float_as_int(v), CTRL, 0xF, 0xF, true);
  return v + __int_as_float(sw);
}

// Butterfly allreduce over each aligned 16-lane group, all full-rate DPP:
// xor1 (quad_perm 0xB1), xor2 (quad_perm 0x4E), row_half_mirror (0x141),
// row_mirror (0x140). All 16 lanes end bitwise identical (verified R2-R11).
__device__ __forceinline__ float allred16(float v) {
  v = dpp_add<0xB1>(v);
  v = dpp_add<0x4E>(v);
  v = dpp_add<0x141>(v);
  v = dpp_add<0x140>(v);
  return v;
}

__global__ __launch_bounds__(256) void gait_all(
    const float* __restrict__ x,
    const float* __restrict__ We1, const float* __restrict__ be1,
    const float* __restrict__ We2, const float* __restrict__ be2,
    const float* __restrict__ We3, const float* __restrict__ be3,
    const float* __restrict__ Wo1, const float* __restrict__ bo1,
    const float* __restrict__ Wo2, const float* __restrict__ bo2,
    const float* __restrict__ Wd,  const float* __restrict__ bd,
    float* __restrict__ out)
{
  const int tid = threadIdx.x;
  const int t   = blockIdx.x * 256 + tid;
  const int b   = t >> 4;    // global sample id
  const int sub = t & 15;    // lane within the sample's 16-lane group
  const int sg  = tid >> 4;  // sample index within block (0..15)

  __shared__ float4 bndl[NSEG + 1][16];  // boundary (za,zb,fa,fb) per sample

  // ---------------- encoder, loop-interchanged (R4) ----------------
  const float* xb = x + (size_t)b * 2304;  // x[b, 0, :], row stride 256*9
  float xv[9];
#pragma unroll
  for (int i = 0; i < 9; ++i) xv[i] = xb[i];

  const int c0 = sub * 4;
  float s0 = be2[c0+0], s1 = be2[c0+1], s2 = be2[c0+2], s3 = be2[c0+3];
#pragma unroll 4
  for (int i = 0; i < 64; ++i) {
    float h = be1[i];
#pragma unroll
    for (int j = 0; j < 9; ++j) h = fmaf(xv[j], We1[j*64 + i], h);
    h = fmaxf(h, 0.0f);
    const float* w2r = We2 + i*64 + c0;
    s0 = fmaf(h, w2r[0], s0);
    s1 = fmaf(h, w2r[1], s1);
    s2 = fmaf(h, w2r[2], s2);
    s3 = fmaf(h, w2r[3], s3);
  }
  s0 = fmaxf(s0, 0.0f); s1 = fmaxf(s1, 0.0f);
  s2 = fmaxf(s2, 0.0f); s3 = fmaxf(s3, 0.0f);
  float z0a = fmaf(s0, We3[(c0+0)*2+0], fmaf(s1, We3[(c0+1)*2+0],
              fmaf(s2, We3[(c0+2)*2+0],      s3 * We3[(c0+3)*2+0])));
  float z0b = fmaf(s0, We3[(c0+0)*2+1], fmaf(s1, We3[(c0+1)*2+1],
              fmaf(s2, We3[(c0+2)*2+1],      s3 * We3[(c0+3)*2+1])));
  z0a = allred16(z0a) + be3[0];
  z0b = allred16(z0b) + be3[1];

  // write z0 (out[0 .. 32767])
  if (sub == 5) {
    float2 v; v.x = z0a; v.y = z0b;
    *reinterpret_cast<float2*>(out + (size_t)b * 2) = v;
  }

  // this lane's 2-wide slice of the 32 hidden units of the vector field
  float w1a[2], w1b[2], b1s[2], w2a[2], w2b[2];
  const int u0 = sub * 2;
#pragma unroll
  for (int q = 0; q < 2; ++q) {
    w1a[q] = Wo1[      u0 + q] * SCALE;   // Wo1[0][u]
    w1b[q] = Wo1[32 +  u0 + q] * SCALE;   // Wo1[1][u]
    b1s[q] = bo1[      u0 + q] * SCALE;
    w2a[q] = Wo2[(u0 + q)*2 + 0];
    w2b[q] = Wo2[(u0 + q)*2 + 1];
  }
  // bo2 folded into lane 0's accumulator init (xor-butterfly keeps all lanes
  // bitwise identical regardless of which lane carries the bias).
  const float a0i = (sub == 0) ? bo2[0] : 0.0f;
  const float a1i = (sub == 0) ? bo2[1] : 0.0f;

  auto vf = [&](float za, float zb, float& o0, float& o1) {
    float a0 = a0i, a1 = a1i;
#pragma unroll
    for (int q = 0; q < 2; ++q) {
      float u  = fmaf(za, w1a[q], fmaf(zb, w1b[q], b1s[q]));
      float e  = fast_exp2(u);
      float rr = fast_rcp(e + 1.0f);
      float th = fmaf(-2.0f, rr, 1.0f);     // tanh
      a0 = fmaf(th, w2a[q], a0);
      a1 = fmaf(th, w2b[q], a1);
    }
    o0 = allred16(a0);
    o1 = allred16(a1);
  };

  float za = z0a, zb = z0b;
  float fa, fb;
  vf(za, zb, fa, fb);        // k1 of first segment (carried across segments)

  const bool storer = (sub == 0);

  // #pragma unroll 1: R3 lesson — compiler unroll exploded VGPRs (52->156).
#pragma unroll 1
  for (int k = 0; k < NSEG; ++k) {
    if (storer) { float4 v; v.x = za; v.y = zb; v.z = fa; v.w = fb;
                  bndl[k][sg] = v; }
    float k2a, k2b, k3a, k3b, k4a, k4b, fna, fnb;
    vf(fmaf(DT2, fa,  za), fmaf(DT2, fb,  zb), k2a, k2b);
    vf(fmaf(DT2, k2a, za), fmaf(DT2, k2b, zb), k3a, k3b);
    vf(fmaf(DT,  k3a, za), fmaf(DT,  k3b, zb), k4a, k4b);
    float zna = fmaf(DT6, fa + k4a + 2.0f*(k2a + k3a), za);
    float znb = fmaf(DT6, fb + k4b + 2.0f*(k2b + k3b), zb);
    vf(zna, znb, fna, fnb);  // next segment's k1 + Hermite end-tangent
    za = zna; zb = znb; fa = fna; fb = fnb;
  }
  if (storer) { float4 v; v.x = za; v.y = zb; v.z = fa; v.w = fb;
                bndl[NSEG][sg] = v; }

  __syncthreads();

  // ---------------- emit phase (arithmetic identical to R10/R11-B) --------
  const float wd0 = Wd[0], wd1 = Wd[1], wd2 = Wd[2];
  const float wd3 = Wd[3], wd4 = Wd[4], wd5 = Wd[5];
  const float bd0 = bd[0], bd1 = bd[1], bd2 = bd[2];

  const int s     = tid & 15;          // sample in block
  const int mpart = tid >> 4;          // 0..15 ; 16 lanes share one m
  const int gb    = blockIdx.x * 16 + s;

  float* __restrict__ zt = out + 32768;
  float* __restrict__ xh = out + 32768 + 8388608;

#pragma unroll 1
  for (int it = 0; it < 16; ++it) {
    const int m = mpart + (it << 4);   // covers 0..255 exactly once
    int k = (m * NSEG) / 255;          // segment; exact integer math
    if (k > NSEG - 1) k = NSEG - 1;    // m=255 -> k=11, th=1
    const float th = fmaf((float)m, K255, -(float)k);

    const float4 p0 = bndl[k][s];
    const float4 p1 = bndl[k + 1][s];

    const float fadt  = DT * p0.z, fbdt  = DT * p0.w;
    const float fnadt = DT * p1.z, fnbdt = DT * p1.w;
    const float da = p1.x - p0.x, db = p1.y - p0.y;
    const float c2a = fmaf(3.f, da, -fmaf(2.f, fadt, fnadt));
    const float c3a = fmaf(-2.f, da, fadt + fnadt);
    const float c2b = fmaf(3.f, db, -fmaf(2.f, fbdt, fnbdt));
    const float c3b = fmaf(-2.f, db, fbdt + fnbdt);

    const float va = fmaf(fmaf(fmaf(c3a, th, c2a), th, fadt), th, p0.x);
    const float vb = fmaf(fmaf(fmaf(c3b, th, c2b), th, fbdt), th, p0.y);

    float2 zv; zv.x = va; zv.y = vb;   // 16 lanes, same m -> 128B contiguous
    *reinterpret_cast<float2*>(zt + ((size_t)m << 15) + 2 * gb) = zv;

    float* q = xh + (size_t)m * 49152 + 3 * gb;
    q[0] = fmaf(va, wd0, fmaf(vb, wd3, bd0));
    q[1] = fmaf(va, wd1, fmaf(vb, wd4, bd1));
    q[2] = fmaf(va, wd2, fmaf(vb, wd5, bd2));
  }
}

extern "C" void kernel_launch(void* const* d_in, const int* in_sizes, int n_in,
                              void* d_out, int out_size, void* d_ws, size_t ws_size,
                              hipStream_t stream)
{
  const float* x   = (const float*)d_in[0];
  const float* We1 = (const float*)d_in[1];
  const float* be1 = (const float*)d_in[2];
  const float* We2 = (const float*)d_in[3];
  const float* be2 = (const float*)d_in[4];
  const float* We3 = (const float*)d_in[5];
  const float* be3 = (const float*)d_in[6];
  const float* Wo1 = (const float*)d_in[7];
  const float* bo1 = (const float*)d_in[8];
  const float* Wo2 = (const float*)d_in[9];
  const float* bo2 = (const float*)d_in[10];
  const float* Wd  = (const float*)d_in[11];
  const float* bd  = (const float*)d_in[12];

  dim3 grid(BATCH * 16 / 256), block(256);
  gait_all<<<grid, block, 0, stream>>>(x, We1, be1, We2, be2, We3, be3,
                                       Wo1, bo1, Wo2, bo2, Wd, bd,
                                       (float*)d_out);
}